// Round 1
// baseline (229.228 us; speedup 1.0000x reference)
//
#include <hip/hip_runtime.h>

#define N_TOK 65536
#define DIN   256
#define DOUT  256
#define NEXP  8
#define NPAIR 28   // C(8,2)

typedef __bf16 bf16x8 __attribute__((ext_vector_type(8)));
typedef float  f32x4  __attribute__((ext_vector_type(4)));

// ---------------------------------------------------------------------------
// prep: Wt[e][n][k] = bf16(We[e][k][n])  (transpose so B-fragments are
// contiguous-in-k 16B LDS reads), and zero the 28 pair counters.
// ---------------------------------------------------------------------------
__global__ __launch_bounds__(256) void prep_kernel(const float* __restrict__ We,
                                                   __bf16* __restrict__ Wt,
                                                   int* __restrict__ cnt) {
  int idx = blockIdx.x * 256 + threadIdx.x;      // 0 .. 524287
  if (blockIdx.x == 0 && threadIdx.x < NPAIR) cnt[threadIdx.x] = 0;
  int e = idx >> 16;
  int r = idx & 0xFFFF;
  int n = r >> 8;
  int k = r & 0xFF;
  Wt[idx] = (__bf16)We[(e << 16) + (k << 8) + n];
}

// ---------------------------------------------------------------------------
// router: fp64-accumulated logits (selection must match np ref exactly),
// top-2 (first-occurrence tie rule = lax.top_k), renormalized weight =
// softmax over the two logits. Append (token, w_of_lower_expert) to the
// expert-PAIR bucket via LDS-aggregated atomics.
// One thread per token; 64-thread blocks.
// ---------------------------------------------------------------------------
__global__ __launch_bounds__(64) void router_kernel(const float* __restrict__ x,
                                                    const float* __restrict__ Wr,
                                                    int* __restrict__ cnt,
                                                    unsigned short* __restrict__ pidx,
                                                    float* __restrict__ pw) {
  __shared__ float WrL[DIN * NEXP];
  __shared__ int lcnt[NPAIR];
  __shared__ int gbase[NPAIR];
  int tid = threadIdx.x;
  for (int j = tid; j < DIN * NEXP / 4; j += 64)
    *(float4*)&WrL[j * 4] = *(const float4*)&Wr[j * 4];
  if (tid < NPAIR) lcnt[tid] = 0;
  __syncthreads();

  int token = blockIdx.x * 64 + tid;
  const float4* xr = (const float4*)(x + (size_t)token * DIN);
  double acc[NEXP];
#pragma unroll
  for (int e = 0; e < NEXP; e++) acc[e] = 0.0;

#pragma unroll 2
  for (int i4 = 0; i4 < DIN / 4; i4++) {
    float4 xv = xr[i4];
#pragma unroll
    for (int u = 0; u < 4; u++) {
      float xf = (u == 0) ? xv.x : (u == 1) ? xv.y : (u == 2) ? xv.z : xv.w;
      double xd = (double)xf;
      const float* wrow = &WrL[(i4 * 4 + u) * NEXP];  // broadcast LDS read
#pragma unroll
      for (int e = 0; e < NEXP; e++) acc[e] = fma(xd, (double)wrow[e], acc[e]);
    }
  }

  // top-2, first occurrence wins ties (matches lax.top_k)
  int best = 0;
#pragma unroll
  for (int e = 1; e < NEXP; e++) if (acc[e] > acc[best]) best = e;
  int sec = (best == 0) ? 1 : 0;
#pragma unroll
  for (int e = 0; e < NEXP; e++)
    if (e != best && e != sec && acc[e] > acc[sec]) sec = e;

  // renormalized top-2 softmax weight of `best`
  float wb = 1.f / (1.f + expf((float)(acc[sec] - acc[best])));
  int a, b; float wa;
  if (best < sec) { a = best; b = sec; wa = wb; }
  else           { a = sec;  b = best; wa = 1.f - wb; }
  int p = a * (15 - a) / 2 + (b - a - 1);          // pair index, 0..27

  int lpos = atomicAdd(&lcnt[p], 1);
  __syncthreads();
  if (tid < NPAIR) gbase[tid] = atomicAdd(&cnt[tid], lcnt[tid]);
  __syncthreads();
  int pos = gbase[p] + lpos;
  pidx[p * N_TOK + pos] = (unsigned short)token;
  pw[p * N_TOK + pos] = wa;
}

// ---------------------------------------------------------------------------
// grouped GEMM over pair buckets. Tile: 128 tokens x 128 cols (nh = col half),
// K = 512 (= [w_a*x | w_b*x] @ [We_a ; We_b]). bf16 MFMA 16x16x32, 4 waves
// in a 2x2 grid, each wave 64x64 (4x4 fragments). LDS stride 72 (+8 pad):
// 36-bank stride tiles all 32 banks -> conflict-free ds_read_b128.
// Output written exactly once (no atomics, no memset).
// ---------------------------------------------------------------------------
__device__ inline bf16x8 cvt8(float4 a, float4 b, float s) {
  bf16x8 v;
  v[0] = (__bf16)(a.x * s); v[1] = (__bf16)(a.y * s);
  v[2] = (__bf16)(a.z * s); v[3] = (__bf16)(a.w * s);
  v[4] = (__bf16)(b.x * s); v[5] = (__bf16)(b.y * s);
  v[6] = (__bf16)(b.z * s); v[7] = (__bf16)(b.w * s);
  return v;
}

__global__ __launch_bounds__(256) void moe_gemm_kernel(const float* __restrict__ x,
                                                       const __bf16* __restrict__ Wt,
                                                       const float* __restrict__ be,
                                                       const int* __restrict__ cnt,
                                                       const unsigned short* __restrict__ pidx,
                                                       const float* __restrict__ pw,
                                                       float* __restrict__ out) {
  __shared__ __bf16 As[128 * 72];
  __shared__ __bf16 Bs[128 * 72];
  __shared__ unsigned short tokL[128];
  __shared__ float wL[128];
  __shared__ int meta[4];

  int tid = threadIdx.x;
  int tile = blockIdx.x >> 1;
  int nh = blockIdx.x & 1;

  if (tid == 0) {
    int s = 0, p = -1, lt = 0, c = 0;
    for (int q = 0; q < NPAIR; q++) {
      int cq = cnt[q];
      int tq = (cq + 127) >> 7;
      if (tile < s + tq) { p = q; lt = tile - s; c = cq; break; }
      s += tq;
    }
    meta[0] = p; meta[1] = lt; meta[2] = c;
  }
  __syncthreads();
  int p = meta[0];
  if (p < 0) return;                 // uniform across block
  int lt = meta[1], cnt_p = meta[2];

  // decode pair p -> (a < b)
  int a = 0, rem = p;
  while (rem >= 7 - a) { rem -= 7 - a; a++; }
  int b = a + 1 + rem;
  int r0 = lt * 128;

  if (tid < 128) {
    int gr = r0 + tid;
    unsigned short t = 0; float wv = 0.f;
    if (gr < cnt_p) { t = pidx[p * N_TOK + gr]; wv = pw[p * N_TOK + gr]; }
    tokL[tid] = t; wL[tid] = wv;     // invalid rows: token 0, w=0 (never stored)
  }
  __syncthreads();

  const int lane = tid & 63, wid = tid >> 6;
  const int wm = wid & 1, wn = wid >> 1;
  const int c16 = lane & 15, quad = lane >> 4;

  f32x4 acc[4][4];
#pragma unroll
  for (int mi = 0; mi < 4; mi++)
#pragma unroll
    for (int ni = 0; ni < 4; ni++)
#pragma unroll
      for (int r = 0; r < 4; r++) acc[mi][ni][r] = 0.f;

  const int rowA = tid >> 1, segA = tid & 1;   // 2 threads per row, 32 elems each

  for (int kc = 0; kc < 8; kc++) {
    int kx = (kc & 3) * 64;
    int eSel = (kc < 4) ? a : b;
    // ---- A stage: gather x rows, scale by per-(token,expert) weight, cvt bf16
    {
      float wrow = wL[rowA];
      if (kc >= 4) wrow = 1.f - wrow;
      const float4* src = (const float4*)(x + (size_t)tokL[rowA] * DIN + kx + segA * 32);
      float4 f0 = src[0], f1 = src[1], f2 = src[2], f3 = src[3];
      float4 f4 = src[4], f5 = src[5], f6 = src[6], f7 = src[7];
      __bf16* dst = &As[rowA * 72 + segA * 32];
      *(bf16x8*)(dst + 0)  = cvt8(f0, f1, wrow);
      *(bf16x8*)(dst + 8)  = cvt8(f2, f3, wrow);
      *(bf16x8*)(dst + 16) = cvt8(f4, f5, wrow);
      *(bf16x8*)(dst + 24) = cvt8(f6, f7, wrow);
    }
    // ---- B stage: copy Wt[eSel][nh*128 + n][kx .. kx+63] (already bf16, [n][k])
    {
      const int4* bsrc = (const int4*)(Wt + (size_t)((eSel * 256 + nh * 128 + rowA) * 256) + kx + segA * 32);
      int4* dstb = (int4*)&Bs[rowA * 72 + segA * 32];
      dstb[0] = bsrc[0]; dstb[1] = bsrc[1]; dstb[2] = bsrc[2]; dstb[3] = bsrc[3];
    }
    __syncthreads();
#pragma unroll
    for (int ks = 0; ks < 2; ks++) {
      bf16x8 af[4], bfv[4];
#pragma unroll
      for (int mi = 0; mi < 4; mi++)
        af[mi] = *(const bf16x8*)&As[(wm * 64 + mi * 16 + c16) * 72 + ks * 32 + quad * 8];
#pragma unroll
      for (int ni = 0; ni < 4; ni++)
        bfv[ni] = *(const bf16x8*)&Bs[(wn * 64 + ni * 16 + c16) * 72 + ks * 32 + quad * 8];
#pragma unroll
      for (int mi = 0; mi < 4; mi++)
#pragma unroll
        for (int ni = 0; ni < 4; ni++)
          acc[mi][ni] = __builtin_amdgcn_mfma_f32_16x16x32_bf16(af[mi], bfv[ni], acc[mi][ni], 0, 0, 0);
    }
    __syncthreads();
  }

  // ---- epilogue: + w_a*be_a + w_b*be_b, store final fp32 (exactly once)
#pragma unroll
  for (int ni = 0; ni < 4; ni++) {
    int gcol = nh * 128 + wn * 64 + ni * 16 + c16;
    float bea = be[a * DOUT + gcol];
    float beb = be[b * DOUT + gcol];
#pragma unroll
    for (int mi = 0; mi < 4; mi++) {
#pragma unroll
      for (int r = 0; r < 4; r++) {
        int row = wm * 64 + mi * 16 + quad * 4 + r;
        if (r0 + row < cnt_p) {
          float wa = wL[row];
          float v = acc[mi][ni][r] + wa * bea + (1.f - wa) * beb;
          out[(size_t)tokL[row] * DOUT + gcol] = v;
        }
      }
    }
  }
}

// ---------------------------------------------------------------------------
extern "C" void kernel_launch(void* const* d_in, const int* in_sizes, int n_in,
                              void* d_out, int out_size, void* d_ws, size_t ws_size,
                              hipStream_t stream) {
  const float* x  = (const float*)d_in[0];
  const float* Wr = (const float*)d_in[1];
  const float* We = (const float*)d_in[2];
  const float* be = (const float*)d_in[3];
  float* out = (float*)d_out;

  // ws layout (needs ~11.6 MB):
  //   [0, 1MB)                       : Wt bf16  [8][256][256]  ([e][n][k])
  //   [1MB, +512B)                   : cnt[28]
  //   [+, +3.5MB)                    : pidx  ushort [28][65536]
  //   [+, +7MB)                      : pw    float  [28][65536]
  char* w = (char*)d_ws;
  __bf16* Wt = (__bf16*)w;
  int* cnt = (int*)(w + (1 << 20));
  unsigned short* pidx = (unsigned short*)(w + (1 << 20) + 512);
  float* pw = (float*)(w + (1 << 20) + 512 + (size_t)NPAIR * N_TOK * 2);

  prep_kernel<<<2048, 256, 0, stream>>>(We, Wt, cnt);
  router_kernel<<<N_TOK / 64, 64, 0, stream>>>(x, Wr, cnt, pidx, pw);
  // max tiles = sum_p ceil(cnt_p/128) <= 65536/128 + 28 = 540; x2 column halves
  moe_gemm_kernel<<<540 * 2, 256, 0, stream>>>(x, Wt, be, cnt, pidx, pw, out);
}

// Round 2
// 224.150 us; speedup vs baseline: 1.0227x; 1.0227x over previous
//
#include <hip/hip_runtime.h>

#define N_TOK 65536
#define DIN   256
#define DOUT  256
#define NEXP  8
#define NPAIR 28   // C(8,2)

typedef __bf16 bf16x8 __attribute__((ext_vector_type(8)));
typedef __bf16 bf16x4 __attribute__((ext_vector_type(4)));
typedef float  f32x4  __attribute__((ext_vector_type(4)));

// global -> LDS async DMA, 16B per lane. LDS dst is wave-uniform base + lane*16
// (HW takes readfirstlane of the pointer); pass each lane's own &lds[slot*8].
__device__ __forceinline__ void cp16_g2l(const void* g, void* l) {
  auto gp = (const __attribute__((address_space(1))) unsigned int*)(unsigned long long)g;
  auto lp = (__attribute__((address_space(3))) unsigned int*)(unsigned long long)l;
  __builtin_amdgcn_global_load_lds(gp, lp, 16, 0, 0);
}

// ---------------------------------------------------------------------------
// prep: Wt[e][n][k] = bf16(We[e][k][n]) via LDS-tiled transpose (coalesced
// both directions), and zero the 28 pair counters.
// grid = 8 experts * 16 tiles of 64x64, block = 256.
// ---------------------------------------------------------------------------
__global__ __launch_bounds__(256) void prep_kernel(const float* __restrict__ We,
                                                   __bf16* __restrict__ Wt,
                                                   int* __restrict__ cnt) {
  __shared__ float T[64 * 65];
  int bid = blockIdx.x;
  if (bid == 0 && threadIdx.x < NPAIR) cnt[threadIdx.x] = 0;
  int e = bid >> 4;
  int tk = (bid >> 2) & 3, tn = bid & 3;
  int k0 = tk * 64, n0 = tn * 64;
  int tid = threadIdx.x;
  int cr = tid >> 6;     // 0..3
  int cc = tid & 63;     // coalesced lane dim
#pragma unroll
  for (int i = 0; i < 16; i++) {
    int k = i * 4 + cr;
    T[cc * 65 + k] = We[(size_t)(e * 256 + k0 + k) * 256 + n0 + cc];  // read n-contig
  }
  __syncthreads();
#pragma unroll
  for (int i = 0; i < 16; i++) {
    int n = i * 4 + cr;
    Wt[(size_t)(e * 256 + n0 + n) * 256 + k0 + cc] = (__bf16)T[n * 65 + cc];  // write k-contig
  }
}

// ---------------------------------------------------------------------------
// router: fp32 logits (np-selection-safe via fp64 recompute when the 2nd/3rd
// gap < 5e-3; 1st/2nd order is output-invariant). Also emits xb = bf16(x).
// Per-pair bucket append with block-aggregated atomics (256-deep, not 1024).
// block = 256 threads = 256 tokens, grid = 256.
// ---------------------------------------------------------------------------
__global__ __launch_bounds__(256) void router_kernel(const float* __restrict__ x,
                                                     const float* __restrict__ Wr,
                                                     __bf16* __restrict__ xb,
                                                     int* __restrict__ cnt,
                                                     unsigned short* __restrict__ pidx,
                                                     float* __restrict__ pw) {
  __shared__ float WrL[DIN * NEXP];
  __shared__ int lcnt[NPAIR];
  __shared__ int gbase[NPAIR];
  int tid = threadIdx.x;
  for (int j = tid; j < DIN * NEXP / 4; j += 256)
    *(float4*)&WrL[j * 4] = *(const float4*)&Wr[j * 4];
  if (tid < NPAIR) lcnt[tid] = 0;
  __syncthreads();

  int token = blockIdx.x * 256 + tid;
  const float4* xr = (const float4*)(x + (size_t)token * DIN);
  __bf16* xbr = xb + (size_t)token * DIN;

  float acc[NEXP];
#pragma unroll
  for (int e = 0; e < NEXP; e++) acc[e] = 0.f;

#pragma unroll 8
  for (int i4 = 0; i4 < DIN / 4; i4++) {
    float4 v = xr[i4];
    bf16x4 bv;
    bv[0] = (__bf16)v.x; bv[1] = (__bf16)v.y; bv[2] = (__bf16)v.z; bv[3] = (__bf16)v.w;
    *(bf16x4*)(xbr + i4 * 4) = bv;
    const float* w0 = &WrL[(i4 * 4) * NEXP];
#pragma unroll
    for (int e = 0; e < NEXP; e++)
      acc[e] += v.x * w0[e] + v.y * w0[NEXP + e] + v.z * w0[2 * NEXP + e] + v.w * w0[3 * NEXP + e];
  }

  int best = 0;
#pragma unroll
  for (int e = 1; e < NEXP; e++) if (acc[e] > acc[best]) best = e;
  int sec = (best == 0) ? 1 : 0;
#pragma unroll
  for (int e = 0; e < NEXP; e++)
    if (e != best && e != sec && acc[e] > acc[sec]) sec = e;
  float l3 = -1e30f;
#pragma unroll
  for (int e = 0; e < NEXP; e++)
    if (e != best && e != sec) l3 = fmaxf(l3, acc[e]);

  float diff = acc[sec] - acc[best];       // <= 0
  bool need = (acc[sec] - l3) < 5e-3f;     // 2nd-vs-3rd near-tie -> fp64
  if (__any(need)) {
    if (need) {
      double d[NEXP];
#pragma unroll
      for (int e = 0; e < NEXP; e++) d[e] = 0.0;
      for (int i4 = 0; i4 < DIN / 4; i4++) {
        float4 v = xr[i4];
        const float* w0 = &WrL[(i4 * 4) * NEXP];
#pragma unroll
        for (int e = 0; e < NEXP; e++)
          d[e] += (double)v.x * w0[e] + (double)v.y * w0[NEXP + e] +
                  (double)v.z * w0[2 * NEXP + e] + (double)v.w * w0[3 * NEXP + e];
      }
      best = 0;
#pragma unroll
      for (int e = 1; e < NEXP; e++) if (d[e] > d[best]) best = e;
      sec = (best == 0) ? 1 : 0;
#pragma unroll
      for (int e = 0; e < NEXP; e++)
        if (e != best && e != sec && d[e] > d[sec]) sec = e;
      diff = (float)(d[sec] - d[best]);
    }
  }

  float wb = 1.f / (1.f + expf(diff));     // weight of `best` after renorm
  int a, b2; float wa;
  if (best < sec) { a = best; b2 = sec; wa = wb; }
  else            { a = sec;  b2 = best; wa = 1.f - wb; }
  int p = a * (15 - a) / 2 + (b2 - a - 1);

  int lpos = atomicAdd(&lcnt[p], 1);
  __syncthreads();
  if (tid < NPAIR) gbase[tid] = atomicAdd(&cnt[tid], lcnt[tid]);
  __syncthreads();
  int pos = gbase[p] + lpos;
  pidx[p * N_TOK + pos] = (unsigned short)token;
  pw[p * N_TOK + pos] = wa;
}

// ---------------------------------------------------------------------------
// grouped GEMM, dual-accumulator form: out = wa*(x@Wa + ba) + wb*(x@Wb + bb).
// Block tile: 128 tokens x 64 cols (nh in 0..3), K=256 in 4 chunks of 64.
// A (xb rows) staged via async global_load_lds with XOR-octet swizzle
// (conflict-free ds_read_b128, no padding needed). B read direct from global
// (Wt is 1MB, L1/L2-hot). 4 waves: 2x2 over (64 tok x 32 cols), dual 4x2 acc.
// Output written exactly once, no atomics.
// ---------------------------------------------------------------------------
__global__ __launch_bounds__(256) void moe_gemm_kernel(const __bf16* __restrict__ xb,
                                                       const __bf16* __restrict__ Wt,
                                                       const float* __restrict__ be,
                                                       const int* __restrict__ cnt,
                                                       const unsigned short* __restrict__ pidx,
                                                       const float* __restrict__ pw,
                                                       float* __restrict__ out) {
  // As slot layout: (row r, octet j') at byte offset (r*8 + j')*16 where the
  // octet stored in slot j' is s8 = j' ^ (r&7)  (XOR swizzle -> all 32 banks).
  __shared__ __bf16 As[128 * 64];
  __shared__ unsigned short tokL[128];
  __shared__ float wL[128];
  __shared__ int meta[4];

  int tid = threadIdx.x;
  int tile = blockIdx.x >> 2;
  int nh = blockIdx.x & 3;

  if (tid == 0) {
    int s = 0, pp = -1, lt = 0, c = 0;
    for (int q = 0; q < NPAIR; q++) {
      int cq = cnt[q];
      int tq = (cq + 127) >> 7;
      if (tile < s + tq) { pp = q; lt = tile - s; c = cq; break; }
      s += tq;
    }
    meta[0] = pp; meta[1] = lt; meta[2] = c;
  }
  __syncthreads();
  int p = meta[0];
  if (p < 0) return;
  int lt = meta[1], cnt_p = meta[2];

  int a = 0, rem = p;
  while (rem >= 7 - a) { rem -= 7 - a; a++; }
  int b2 = a + 1 + rem;
  int r0 = lt * 128;

  if (tid < 128) {
    int gr = r0 + tid;
    tokL[tid] = (gr < cnt_p) ? pidx[p * N_TOK + gr] : (unsigned short)0;
    wL[tid]   = (gr < cnt_p) ? pw[p * N_TOK + gr] : 0.f;
  }
  __syncthreads();

  const int lane = tid & 63, wid = tid >> 6;
  const int wm = wid & 1, wn = wid >> 1;
  const int c16 = lane & 15, quad = lane >> 4;

  // staging geometry: thread handles slots tid + 256*i -> row r = tid>>3 + 32*i,
  // slot-octet j' = tid&7, global octet s8 = j' ^ (r&7) (r&7 same for all i).
  const int r_base = tid >> 3;
  const int s8 = (tid & 7) ^ (r_base & 7);
  size_t grow[4];
#pragma unroll
  for (int i = 0; i < 4; i++)
    grow[i] = (size_t)tokL[r_base + 32 * i] * DIN + s8 * 8;

  const __bf16* WtA = Wt + ((size_t)a * DOUT + nh * 64) * DIN;
  const __bf16* WtB = Wt + ((size_t)b2 * DOUT + nh * 64) * DIN;

  f32x4 accA[4][2], accB[4][2];
#pragma unroll
  for (int mi = 0; mi < 4; mi++)
#pragma unroll
    for (int ni = 0; ni < 2; ni++)
#pragma unroll
      for (int r = 0; r < 4; r++) { accA[mi][ni][r] = 0.f; accB[mi][ni][r] = 0.f; }

  for (int kc = 0; kc < 4; kc++) {
#pragma unroll
    for (int i = 0; i < 4; i++) {
      int slot = tid + 256 * i;
      cp16_g2l(xb + grow[i] + kc * 64, &As[slot * 8]);
    }
    __builtin_amdgcn_s_waitcnt(0x0F70);  // vmcnt(0): DMA landed in LDS
    __syncthreads();
#pragma unroll
    for (int ks = 0; ks < 2; ks++) {
      bf16x8 af[4], ba[2], bb[2];
#pragma unroll
      for (int mi = 0; mi < 4; mi++) {
        int row = wm * 64 + mi * 16 + c16;
        int oct = ks * 4 + quad;
        af[mi] = *(const bf16x8*)&As[(row * 8 + (oct ^ (row & 7))) * 8];
      }
#pragma unroll
      for (int ni = 0; ni < 2; ni++) {
        int col = wn * 32 + ni * 16 + c16;
        int koff = kc * 64 + ks * 32 + quad * 8;
        ba[ni] = *(const bf16x8*)&WtA[(size_t)col * DIN + koff];
        bb[ni] = *(const bf16x8*)&WtB[(size_t)col * DIN + koff];
      }
#pragma unroll
      for (int mi = 0; mi < 4; mi++)
#pragma unroll
        for (int ni = 0; ni < 2; ni++) {
          accA[mi][ni] = __builtin_amdgcn_mfma_f32_16x16x32_bf16(af[mi], ba[ni], accA[mi][ni], 0, 0, 0);
          accB[mi][ni] = __builtin_amdgcn_mfma_f32_16x16x32_bf16(af[mi], bb[ni], accB[mi][ni], 0, 0, 0);
        }
    }
    __syncthreads();
  }

  // epilogue: weights + biases in fp32, store exactly once
#pragma unroll
  for (int ni = 0; ni < 2; ni++) {
    int gcol = nh * 64 + wn * 32 + ni * 16 + c16;
    float bea = be[a * DOUT + gcol];
    float beb = be[b2 * DOUT + gcol];
#pragma unroll
    for (int mi = 0; mi < 4; mi++) {
#pragma unroll
      for (int r = 0; r < 4; r++) {
        int row = wm * 64 + mi * 16 + quad * 4 + r;
        if (r0 + row < cnt_p) {
          float w = wL[row];
          out[(size_t)tokL[row] * DOUT + gcol] =
              w * (accA[mi][ni][r] + bea) + (1.f - w) * (accB[mi][ni][r] + beb);
        }
      }
    }
  }
}

// ---------------------------------------------------------------------------
extern "C" void kernel_launch(void* const* d_in, const int* in_sizes, int n_in,
                              void* d_out, int out_size, void* d_ws, size_t ws_size,
                              hipStream_t stream) {
  const float* x  = (const float*)d_in[0];
  const float* Wr = (const float*)d_in[1];
  const float* We = (const float*)d_in[2];
  const float* be = (const float*)d_in[3];
  float* out = (float*)d_out;

  // ws layout (~44.1 MB):
  //   [0, 1MB)        : Wt  bf16 [8][256][256]  ([e][n][k])
  //   [1MB, 33MB)     : xb  bf16 [65536][256]
  //   [33MB, +512B)   : cnt[28]
  //   [+, +3.5MB)     : pidx ushort [28][65536]
  //   [+, +7MB)       : pw   float  [28][65536]
  char* w = (char*)d_ws;
  __bf16* Wt = (__bf16*)w;
  __bf16* xb = (__bf16*)(w + (1u << 20));
  int* cnt = (int*)(w + (33u << 20));
  unsigned short* pidx = (unsigned short*)(w + (33u << 20) + 512);
  float* pw = (float*)(w + (33u << 20) + 512 + (size_t)NPAIR * N_TOK * 2);

  prep_kernel<<<128, 256, 0, stream>>>(We, Wt, cnt);
  router_kernel<<<N_TOK / 256, 256, 0, stream>>>(x, Wr, xb, cnt, pidx, pw);
  // max tiles = sum_p ceil(cnt_p/128) <= 65536/128 + 28 = 540; x4 column strips
  moe_gemm_kernel<<<540 * 4, 256, 0, stream>>>(xb, Wt, be, cnt, pidx, pw, out);
}